// Round 4
// baseline (265.421 us; speedup 1.0000x reference)
//
#include <hip/hip_runtime.h>
#include <cmath>

typedef __bf16 bf16_t;
typedef bf16_t bf16x8 __attribute__((ext_vector_type(8)));
typedef bf16_t bf16x4 __attribute__((ext_vector_type(4)));
typedef float  f32x4  __attribute__((ext_vector_type(4)));

#define Bn  4
#define TQn 1024
#define TKn 1024
#define En  1024
#define Hn  16
#define DHn 64

static constexpr float EPSv = 1e-5f;
// softmax in exp2 domain: scale = (1/sqrt(64)) * log2(e)
static constexpr float C_SCALE = 0.18033688011112042f;

#define GLDS16(g, l)                                                         \
    __builtin_amdgcn_global_load_lds(                                        \
        (const __attribute__((address_space(1))) void*)(g),                  \
        (__attribute__((address_space(3))) void*)(l), 16, 0, 0)

// ---------------------------------------------------------------------------
// fp32 -> bf16 conversion, all tensors fused.
// ---------------------------------------------------------------------------
__global__ __launch_bounds__(256)
void cvt_all(const float* __restrict__ x, const float* __restrict__ enc,
             const float* __restrict__ q1w, const float* __restrict__ q2w,
             const float* __restrict__ k1w, const float* __restrict__ k2w,
             const float* __restrict__ vw,  const float* __restrict__ outw,
             bf16_t* __restrict__ xb, bf16_t* __restrict__ encb,
             bf16_t* __restrict__ wq, bf16_t* __restrict__ wkv,
             bf16_t* __restrict__ wob)
{
    int idx = blockIdx.x * 256 + threadIdx.x;   // 0 .. 3670015
    const float* src; bf16_t* dst;
    if      (idx < 1048576) { src = x    + (size_t)idx * 4;              dst = xb   + (size_t)idx * 4; }
    else if (idx < 2097152) { src = enc  + (size_t)(idx - 1048576) * 4;  dst = encb + (size_t)(idx - 1048576) * 4; }
    else if (idx < 2359296) { src = q1w  + (size_t)(idx - 2097152) * 4;  dst = wq   + (size_t)(idx - 2097152) * 4; }
    else if (idx < 2621440) { src = q2w  + (size_t)(idx - 2359296) * 4;  dst = wq   + 1048576 + (size_t)(idx - 2359296) * 4; }
    else if (idx < 2883584) { src = k1w  + (size_t)(idx - 2621440) * 4;  dst = wkv  + (size_t)(idx - 2621440) * 4; }
    else if (idx < 3145728) { src = k2w  + (size_t)(idx - 2883584) * 4;  dst = wkv  + 1048576 + (size_t)(idx - 2883584) * 4; }
    else if (idx < 3407872) { src = vw   + (size_t)(idx - 3145728) * 4;  dst = wkv  + 2097152 + (size_t)(idx - 3145728) * 4; }
    else                    { src = outw + (size_t)(idx - 3407872) * 4;  dst = wob  + (size_t)(idx - 3407872) * 4; }
    float4 v = *(const float4*)src;
    bf16x4 o;
    o[0] = (bf16_t)v.x; o[1] = (bf16_t)v.y; o[2] = (bf16_t)v.z; o[3] = (bf16_t)v.w;
    *(bf16x4*)dst = o;
}

// ---------------------------------------------------------------------------
// Projection GEMM (m97 recipe) + 2D XCD swizzle: each XCD owns a 20x8 block
// rectangle (W working set 5 MB, A 2 MB) instead of round-robin scatter that
// re-fetched A panels 8x (FETCH was 78 MB vs 18 MB distinct).
// ---------------------------------------------------------------------------
__global__ __launch_bounds__(256, 3)
void gemm_proj(const bf16_t* __restrict__ xb, const bf16_t* __restrict__ encb,
               const bf16_t* __restrict__ wq, const bf16_t* __restrict__ wkv,
               const float* __restrict__ q1b, const float* __restrict__ q2b,
               const float* __restrict__ k1b, const float* __restrict__ k2b,
               const float* __restrict__ vb,
               bf16_t* __restrict__ q12, bf16_t* __restrict__ k12v)
{
    __shared__ bf16_t sA[128 * 64];
    __shared__ bf16_t sB[128 * 64];
    // bijective remap of flat id L (0..1279): xcd = L%8 gets rect
    // bx in [(xcd&1)*20, +20), by in [(xcd>>1)*8, +8)
    const int L = blockIdx.x;
    const int xcd = L & 7, o = L >> 3;          // o in 0..159
    int bx = (xcd & 1) * 20 + (o % 20);
    const int blockM = ((xcd >> 1) * 8 + (o / 20)) << 7;

    const bf16_t* A; const bf16_t* W; bf16_t* C; const float* bp; int blockN;
    if (bx < 16) {
        A = xb; W = wq; C = q12; blockN = bx << 7;
        bp = (blockN >> 10) ? q2b : q1b;
    } else {
        bx -= 16;
        A = encb; W = wkv; C = k12v; blockN = bx << 7;
        const int seg = blockN >> 10;
        bp = (seg == 0) ? k1b : ((seg == 1) ? k2b : vb);
    }

    const int tid = threadIdx.x;
    const int w = tid >> 6, lane = tid & 63;
    const int q = lane >> 4, r = lane & 15;
    const int wm = w & 1, wn = w >> 1;

    f32x4 acc[4][4];
#pragma unroll
    for (int i = 0; i < 4; ++i)
#pragma unroll
        for (int j = 0; j < 4; ++j) acc[i][j] = (f32x4){0.f, 0.f, 0.f, 0.f};

    for (int k0 = 0; k0 < 1024; k0 += 64) {
#pragma unroll
        for (int c = 0; c < 4; ++c) {
            const int s = c * 256 + tid;
            const int row = s >> 3;
            const int cg = (s & 7) ^ (row & 7);
            GLDS16(A + (size_t)(blockM + row) * 1024 + k0 + cg * 8, sA + c * 2048 + w * 512);
            GLDS16(W + (size_t)(blockN + row) * 1024 + k0 + cg * 8, sB + c * 2048 + w * 512);
        }
        __syncthreads();
#pragma unroll
        for (int ks = 0; ks < 2; ++ks) {
            bf16x8 a[4], b[4];
#pragma unroll
            for (int i = 0; i < 4; ++i) {
                const int row = wm * 64 + i * 16 + r;
                const int g = (ks * 4 + q) ^ (row & 7);
                a[i] = *(const bf16x8*)&sA[row * 64 + g * 8];
            }
#pragma unroll
            for (int j = 0; j < 4; ++j) {
                const int row = wn * 64 + j * 16 + r;
                const int g = (ks * 4 + q) ^ (row & 7);
                b[j] = *(const bf16x8*)&sB[row * 64 + g * 8];
            }
#pragma unroll
            for (int i = 0; i < 4; ++i)
#pragma unroll
                for (int j = 0; j < 4; ++j)
                    acc[i][j] = __builtin_amdgcn_mfma_f32_16x16x32_bf16(a[i], b[j], acc[i][j], 0, 0, 0);
        }
        __syncthreads();
    }

    const int seg = blockN >> 10;
#pragma unroll
    for (int j = 0; j < 4; ++j) {
        const int n = blockN + wn * 64 + j * 16 + r;
        const float bv = bp[n & 1023];
#pragma unroll
        for (int i = 0; i < 4; ++i) {
            f32x4 v = acc[i][j];
#pragma unroll
            for (int e = 0; e < 4; ++e) {
                const int m = blockM + wm * 64 + i * 16 + q * 4 + e;
                const float val = v[e] + bv;
                const int bb = m >> 10, t = m & 1023;
                const int h = (n >> 6) & 15, d = n & 63;
                ((bf16_t*)C)[((((size_t)seg * 4 + bb) * 16 + h) * 1024 + t) * 64 + d] = (bf16_t)val;
            }
        }
    }
}

// ---------------------------------------------------------------------------
// Output GEMM: BM=64 x BN=128 tile + bijective XCD swizzle.
// ---------------------------------------------------------------------------
__global__ __launch_bounds__(256, 4)
void gemm_out(const bf16_t* __restrict__ yb, const bf16_t* __restrict__ wob,
              const float* __restrict__ outb, float* __restrict__ out)
{
    __shared__ bf16_t sA[64 * 64];
    __shared__ bf16_t sB[128 * 64];
    const int L = blockIdx.x;
    const int xcd = L & 7, kk = L >> 3;
    const int blockM = (xcd * 8 + (kk >> 3)) * 64;
    const int blockN = (kk & 7) * 128;

    const int tid = threadIdx.x;
    const int w = tid >> 6, lane = tid & 63;
    const int q = lane >> 4, r = lane & 15;

    f32x4 acc[4][2];
#pragma unroll
    for (int i = 0; i < 4; ++i)
#pragma unroll
        for (int j = 0; j < 2; ++j) acc[i][j] = (f32x4){0.f, 0.f, 0.f, 0.f};

    for (int k0 = 0; k0 < 1024; k0 += 64) {
#pragma unroll
        for (int c = 0; c < 2; ++c) {
            const int s = c * 256 + tid;
            const int row = s >> 3;
            const int cg = (s & 7) ^ (row & 7);
            GLDS16(yb + (size_t)(blockM + row) * 1024 + k0 + cg * 8, sA + c * 2048 + w * 512);
        }
#pragma unroll
        for (int c = 0; c < 4; ++c) {
            const int s = c * 256 + tid;
            const int row = s >> 3;
            const int cg = (s & 7) ^ (row & 7);
            GLDS16(wob + (size_t)(blockN + row) * 1024 + k0 + cg * 8, sB + c * 2048 + w * 512);
        }
        __syncthreads();
#pragma unroll
        for (int ks = 0; ks < 2; ++ks) {
            bf16x8 a[4], b[2];
#pragma unroll
            for (int i = 0; i < 4; ++i) {
                const int row = i * 16 + r;
                const int g = (ks * 4 + q) ^ (row & 7);
                a[i] = *(const bf16x8*)&sA[row * 64 + g * 8];
            }
#pragma unroll
            for (int j = 0; j < 2; ++j) {
                const int row = w * 32 + j * 16 + r;
                const int g = (ks * 4 + q) ^ (row & 7);
                b[j] = *(const bf16x8*)&sB[row * 64 + g * 8];
            }
#pragma unroll
            for (int i = 0; i < 4; ++i)
#pragma unroll
                for (int j = 0; j < 2; ++j)
                    acc[i][j] = __builtin_amdgcn_mfma_f32_16x16x32_bf16(a[i], b[j], acc[i][j], 0, 0, 0);
        }
        __syncthreads();
    }

#pragma unroll
    for (int j = 0; j < 2; ++j) {
        const int n = blockN + w * 32 + j * 16 + r;
        const float bv = outb[n];
#pragma unroll
        for (int i = 0; i < 4; ++i) {
            f32x4 v = acc[i][j];
#pragma unroll
            for (int e = 0; e < 4; ++e) {
                const int m = blockM + i * 16 + q * 4 + e;
                out[(size_t)m * 1024 + n] = v[e] + bv;
            }
        }
    }
}

// ---------------------------------------------------------------------------
// Attention phase helpers (transposed-S, 4 waves x 32 q-rows: Round-1 winner)
// ---------------------------------------------------------------------------
__device__ __forceinline__ void compute_S(const bf16_t* __restrict__ sK,
                                          const bf16x8 (&fQ)[2][2],
                                          f32x4 (&S)[4][2], int q, int r)
{
#pragma unroll
    for (int i = 0; i < 4; ++i)
#pragma unroll
        for (int j = 0; j < 2; ++j) S[i][j] = (f32x4){0.f, 0.f, 0.f, 0.f};
#pragma unroll
    for (int ks = 0; ks < 2; ++ks) {
        bf16x8 fK[4];
#pragma unroll
        for (int i = 0; i < 4; ++i) {
            const int row = i * 16 + r;
            const int g = (ks * 4 + q) ^ (row & 7);
            fK[i] = *(const bf16x8*)&sK[row * 64 + g * 8];
        }
        __builtin_amdgcn_s_setprio(1);
#pragma unroll
        for (int i = 0; i < 4; ++i)
#pragma unroll
            for (int j = 0; j < 2; ++j)
                S[i][j] = __builtin_amdgcn_mfma_f32_16x16x32_bf16(fK[i], fQ[j][ks], S[i][j], 0, 0, 0);
        __builtin_amdgcn_s_setprio(0);
    }
}

__device__ __forceinline__ void softmax_pw(f32x4 (&S)[4][2], bf16_t* __restrict__ sPt,
                                           float (&l)[2], int w, int q, int r)
{
#pragma unroll
    for (int j = 0; j < 2; ++j) {
        const int t = w * 32 + j * 16 + r;
        float part = 0.f;
#pragma unroll
        for (int i = 0; i < 4; ++i) {
            bf16x4 pk;
#pragma unroll
            for (int e = 0; e < 4; ++e) {
                const float p = __builtin_amdgcn_exp2f(S[i][j][e] * C_SCALE);
                part += p;
                pk[e] = (bf16_t)p;
            }
            const int sb = i * 16 + q * 4;
            const int g = (sb >> 3) ^ (t & 7);
            *(bf16x4*)&sPt[t * 64 + g * 8 + (sb & 7)] = pk;
        }
        l[j] += part;
    }
}

__device__ __forceinline__ void pv(const bf16_t* __restrict__ sPt,
                                   const bf16x8 (&fV)[4][2],
                                   f32x4 (&O)[2][4], int w, int q, int r)
{
#pragma unroll
    for (int ks = 0; ks < 2; ++ks) {
        bf16x8 fP[2];
#pragma unroll
        for (int i2 = 0; i2 < 2; ++i2) {
            const int m = w * 32 + i2 * 16 + r;
            const int g = (ks * 4 + q) ^ (m & 7);
            fP[i2] = *(const bf16x8*)&sPt[m * 64 + g * 8];
        }
        __builtin_amdgcn_s_setprio(1);
#pragma unroll
        for (int i2 = 0; i2 < 2; ++i2)
#pragma unroll
            for (int j = 0; j < 4; ++j)
                O[i2][j] = __builtin_amdgcn_mfma_f32_16x16x32_bf16(fP[i2], fV[j][ks], O[i2][j], 0, 0, 0);
        __builtin_amdgcn_s_setprio(0);
    }
}

// ---------------------------------------------------------------------------
// Single-stream flash attention block. Grid dim3(64, 8, 2): x = bh (XCD-local
// K/V: linear%8 == bh%8), y = qt, z = stream (0: Q1K1, 1: Q2K2).
// 256 thr, 4 waves x 32 q-rows (Round-1 structure), one softmax stream per
// block -> LDS 41 KB -> 3 blocks/CU = 12 waves/CU, blocks independent.
// Writes O*fac/l as bf16 partials; combine kernel does the subtraction + GN.
// ---------------------------------------------------------------------------
__global__ __launch_bounds__(256, 3)
void attn_stream(const bf16_t* __restrict__ q12, const bf16_t* __restrict__ k12v,
                 const float* __restrict__ lam, bf16_t* __restrict__ opart)
{
    __shared__ bf16_t sK[2][64 * 64];
    __shared__ bf16_t sVt[64 * 64];     // [d][s], swizzled
    __shared__ bf16_t sPt[128 * 64];    // [t][s], wave-private strips
    __shared__ float  sl[128];

    const int tid = threadIdx.x;
    const int w = tid >> 6, lane = tid & 63;
    const int q = lane >> 4, r = lane & 15;
    const int bh = blockIdx.x, qt = blockIdx.y, mat = blockIdx.z;
    const float fac = mat ? lam[bh & (Hn - 1)] : 1.0f;

    const size_t HT = (size_t)TKn * DHn;          // 65536
    const bf16_t* qg = q12 + (size_t)(mat * 64 + bh) * HT + (size_t)qt * 128 * DHn;
    const bf16_t* kg = k12v + (size_t)(mat * 64 + bh) * HT;
    const bf16_t* vg = k12v + (size_t)(128 + bh) * HT;

    // Q fragments in registers (B-operand layout)
    bf16x8 fQ[2][2];
#pragma unroll
    for (int j = 0; j < 2; ++j) {
        const int t = w * 32 + j * 16 + r;
#pragma unroll
        for (int ks = 0; ks < 2; ++ks)
            fQ[j][ks] = *(const bf16x8*)(qg + (size_t)t * 64 + ks * 32 + q * 8);
    }

    f32x4 O[2][4];
    float l[2] = {0.f, 0.f};
#pragma unroll
    for (int i = 0; i < 2; ++i)
#pragma unroll
        for (int j = 0; j < 4; ++j) O[i][j] = (f32x4){0.f,0.f,0.f,0.f};

    // ---- prologue: stage K[0] (buf 0) and V[0] ----
    {
#pragma unroll
        for (int c = 0; c < 2; ++c) {
            const int s = c * 256 + tid;
            const int row = s >> 3;
            const int cg = (s & 7) ^ (row & 7);
            GLDS16(kg + row * 64 + cg * 8, &sK[0][c * 2048 + w * 512]);
        }
        bf16x8 v0[2];
#pragma unroll
        for (int rep = 0; rep < 2; ++rep)
            v0[rep] = *(const bf16x8*)(vg + (size_t)lane * 64 + (w * 2 + rep) * 8);
        __syncthreads();   // K[0] in LDS (vmcnt drained), v0 loaded
#pragma unroll
        for (int rep = 0; rep < 2; ++rep) {
            const int d0 = (w * 2 + rep) * 8;
#pragma unroll
            for (int i = 0; i < 8; ++i) {
                const int d = d0 + i;
                sVt[d * 64 + (((lane >> 3) ^ i) << 3) + (lane & 7)] = v0[rep][i];
            }
        }
        __syncthreads();   // sVt visible
    }

    bf16x8 vr[2];
    for (int st = 0; st < TKn / 64; ++st) {
        const int cur = st & 1;
        // ---- prefetch next tile: K via GLDS dbuf, V into registers ----
        if (st < 15) {
            const bf16_t* kp = kg + (size_t)(st + 1) * 4096;
#pragma unroll
            for (int c = 0; c < 2; ++c) {
                const int s = c * 256 + tid;
                const int row = s >> 3;
                const int cg = (s & 7) ^ (row & 7);
                GLDS16(kp + row * 64 + cg * 8, &sK[cur ^ 1][c * 2048 + w * 512]);
            }
            const bf16_t* vp = vg + (size_t)(st + 1) * 4096;
#pragma unroll
            for (int rep = 0; rep < 2; ++rep)
                vr[rep] = *(const bf16x8*)(vp + (size_t)lane * 64 + (w * 2 + rep) * 8);
        }

        // ---- compute on current tile ----
        {
            f32x4 S[4][2];
            compute_S(sK[cur], fQ, S, q, r);
            softmax_pw(S, sPt, l, w, q, r);
        }
        bf16x8 fV[4][2];
#pragma unroll
        for (int j = 0; j < 4; ++j)
#pragma unroll
            for (int ks = 0; ks < 2; ++ks) {
                const int d = j * 16 + r;
                const int g = (ks * 4 + q) ^ (d & 7);
                fV[j][ks] = *(const bf16x8*)&sVt[d * 64 + g * 8];
            }
        pv(sPt, fV, O, w, q, r);

        __syncthreads();   // all waves done with sVt & sK[cur]; prefetches drained
        if (st < 15) {
#pragma unroll
            for (int rep = 0; rep < 2; ++rep) {
                const int d0 = (w * 2 + rep) * 8;
#pragma unroll
                for (int i = 0; i < 8; ++i) {
                    const int d = d0 + i;
                    sVt[d * 64 + (((lane >> 3) ^ i) << 3) + (lane & 7)] = vr[rep][i];
                }
            }
            __syncthreads();   // sVt[st+1] visible
        }
    }

    // ---- l reduction across q-groups ----
#pragma unroll
    for (int j = 0; j < 2; ++j) {
        float v1 = l[j];
        v1 += __shfl_xor(v1, 16); v1 += __shfl_xor(v1, 32);
        if (q == 0) sl[w * 32 + j * 16 + r] = v1;
    }
    __syncthreads();

    // ---- epilogue: write fac * O / l as bf16 partials ----
    bf16_t* op = opart + (size_t)mat * 4194304 + ((size_t)bh * TQn + (size_t)qt * 128) * DHn;
#pragma unroll
    for (int i2 = 0; i2 < 2; ++i2)
#pragma unroll
        for (int e = 0; e < 4; ++e) {
            const int t = w * 32 + i2 * 16 + q * 4 + e;
            const float inv = fac / sl[t];
#pragma unroll
            for (int j = 0; j < 4; ++j)
                op[(size_t)t * 64 + j * 16 + r] = (bf16_t)(O[i2][j][e] * inv);
        }
}

// ---------------------------------------------------------------------------
// Combine: o = o1 - o2 (bf16 partials), emit GN per-block partial sums.
// Each 256-thr block covers 2048 contiguous elems -> exactly one bh;
// 32 blocks per bh -> stats slots [bh][0..32) sums, +2048 offset for sq.
// GRID MUST BE 2048 (4,194,304 elems / 2048 per block).
// ---------------------------------------------------------------------------
__global__ __launch_bounds__(256)
void combine(const bf16_t* __restrict__ opart, bf16_t* __restrict__ attnb,
             float* __restrict__ stats)
{
    __shared__ float sred[8];
    const int tid = threadIdx.x;
    const int f = blockIdx.x * 256 + tid;
    const size_t base = (size_t)f * 8;
    bf16x8 a = *(const bf16x8*)&opart[base];
    bf16x8 b = *(const bf16x8*)&opart[4194304 + base];
    bf16x8 o;
    float ssum = 0.f, ssq = 0.f;
#pragma unroll
    for (int i = 0; i < 8; ++i) {
        const float v = (float)a[i] - (float)b[i];
        o[i] = (bf16_t)v;
        ssum += v;
        ssq += v * v;
    }
    *(bf16x8*)&attnb[base] = o;
#pragma unroll
    for (int d = 1; d < 64; d <<= 1) {
        ssum += __shfl_xor(ssum, d);
        ssq  += __shfl_xor(ssq, d);
    }
    const int w = tid >> 6;
    if ((tid & 63) == 0) { sred[w] = ssum; sred[4 + w] = ssq; }
    __syncthreads();
    if (tid == 0) {
        const int bh = blockIdx.x >> 5;
        const int slot = blockIdx.x & 31;
        stats[bh * 32 + slot]        = sred[0] + sred[1] + sred[2] + sred[3];
        stats[2048 + bh * 32 + slot] = sred[4] + sred[5] + sred[6] + sred[7];
    }
}

// ---------------------------------------------------------------------------
// GroupNorm apply (mu/rstd from 32 per-block partials) + transpose -> y bf16
// ---------------------------------------------------------------------------
__global__ __launch_bounds__(256)
void gn_apply(const bf16_t* __restrict__ attn, const float* __restrict__ stats,
              const float* __restrict__ gamma, const float* __restrict__ beta,
              bf16_t* __restrict__ y)
{
    const int f = blockIdx.x * 256 + threadIdx.x;   // 8-elem group, 0..524287
    const int d8 = (f & 7) << 3;
    const int t  = (f >> 3) & 1023;
    const int bh = f >> 13;
    const int h  = bh & 15;
    const int b  = bh >> 4;
    const float* p1 = stats + bh * 32;
    const float* p2 = stats + 2048 + bh * 32;
    float s1 = 0.f, s2 = 0.f;
#pragma unroll
    for (int k = 0; k < 8; ++k) {
        float4 u1 = *(const float4*)&p1[k * 4];
        float4 u2 = *(const float4*)&p2[k * 4];
        s1 += u1.x + u1.y + u1.z + u1.w;
        s2 += u2.x + u2.y + u2.z + u2.w;
    }
    const float mu = s1 * (1.f / 65536.f);
    const float var = s2 * (1.f / 65536.f) - mu * mu;
    const float rstd = rsqrtf(var + EPSv);
    bf16x8 v = *(const bf16x8*)&attn[((size_t)bh << 16) + t * 64 + d8];
    const int c = h * 64 + d8;
    const float* gp = gamma + c;
    const float* bp = beta + c;
    bf16x8 o;
#pragma unroll
    for (int i = 0; i < 8; ++i)
        o[i] = (bf16_t)(((float)v[i] - mu) * rstd * gp[i] + bp[i]);
    *(bf16x8*)&y[((size_t)(b * 1024 + t)) * 1024 + c] = o;
}

// ---------------------------------------------------------------------------
extern "C" void kernel_launch(void* const* d_in, const int* in_sizes, int n_in,
                              void* d_out, int out_size, void* d_ws, size_t ws_size,
                              hipStream_t stream)
{
    const float* x    = (const float*)d_in[0];
    const float* enc  = (const float*)d_in[1];
    const float* Q1w  = (const float*)d_in[2];
    const float* Q1b  = (const float*)d_in[3];
    const float* Q2w  = (const float*)d_in[4];
    const float* Q2b  = (const float*)d_in[5];
    const float* K1w  = (const float*)d_in[6];
    const float* K1b  = (const float*)d_in[7];
    const float* K2w  = (const float*)d_in[8];
    const float* K2b  = (const float*)d_in[9];
    const float* Vw   = (const float*)d_in[10];
    const float* Vb   = (const float*)d_in[11];
    const float* lam  = (const float*)d_in[12];
    const float* gng  = (const float*)d_in[13];
    const float* gnb  = (const float*)d_in[14];
    const float* outw = (const float*)d_in[15];
    const float* outb = (const float*)d_in[16];
    float* out = (float*)d_out;

    // workspace layout (bf16 elems). Peak footprint 68 MB.
    // Liveness: xb/encb/wq/wkv dead after proj -> reused for opart/attnb/stats/yb.
    bf16_t* xb   = (bf16_t*)d_ws;            // 4,194,304   live k1..k2
    bf16_t* encb = xb   + 4194304;           // 4,194,304   live k1..k2
    bf16_t* wq   = encb + 4194304;           // 2,097,152   live k1..k2  [Q1w|Q2w]
    bf16_t* wkv  = wq   + 2097152;           // 3,145,728   live k1..k2  [K1w|K2w|Vw]
    bf16_t* wob  = wkv  + 3145728;           // 1,048,576   live k1..k6
    bf16_t* q12  = wob  + 1048576;           // 8,388,608   live k2..k3  [2][B][H][T][D]
    bf16_t* k12v = q12  + 8388608;           // 12,582,912  live k2..k3  [3][B][H][T][D]
    bf16_t* opart= xb;                       // alias: [2][bh][t][d] bf16 = xb+encb, k3 -> k4
    bf16_t* attnb= wq;                       // alias: 4,194,304 elems = wq + 2/3 of wkv, k4 -> k5
    float*  stats= (float*)(wq + 4194304);   // alias: 4096 f32 in wkv tail, k4 -> k5
    bf16_t* yb   = xb;                       // alias: written k5, read k6 (opart dead)

    cvt_all<<<14336, 256, 0, stream>>>(x, enc, Q1w, Q2w, K1w, K2w, Vw, outw,
                                       xb, encb, wq, wkv, wob);

    gemm_proj<<<1280, 256, 0, stream>>>(xb, encb, wq, wkv,
                                        Q1b, Q2b, K1b, K2b, Vb, q12, k12v);

    attn_stream<<<dim3(64, 8, 2), 256, 0, stream>>>(q12, k12v, lam, opart);

    combine<<<2048, 256, 0, stream>>>(opart, attnb, stats);

    gn_apply<<<2048, 256, 0, stream>>>(attnb, stats, gng, gnb, yb);

    gemm_out<<<512, 256, 0, stream>>>(yb, wob, outb, out);
}

// Round 5
// 249.544 us; speedup vs baseline: 1.0636x; 1.0636x over previous
//
#include <hip/hip_runtime.h>
#include <cmath>

typedef __bf16 bf16_t;
typedef bf16_t bf16x8 __attribute__((ext_vector_type(8)));
typedef bf16_t bf16x4 __attribute__((ext_vector_type(4)));
typedef float  f32x4  __attribute__((ext_vector_type(4)));

#define Bn  4
#define TQn 1024
#define TKn 1024
#define En  1024
#define Hn  16
#define DHn 64

static constexpr float EPSv = 1e-5f;
// softmax in exp2 domain: scale = (1/sqrt(64)) * log2(e)
static constexpr float C_SCALE = 0.18033688011112042f;

#define GLDS16(g, l)                                                         \
    __builtin_amdgcn_global_load_lds(                                        \
        (const __attribute__((address_space(1))) void*)(g),                  \
        (__attribute__((address_space(3))) void*)(l), 16, 0, 0)

// ---------------------------------------------------------------------------
// fp32 -> bf16 conversion, all tensors fused.
// ---------------------------------------------------------------------------
__global__ __launch_bounds__(256)
void cvt_all(const float* __restrict__ x, const float* __restrict__ enc,
             const float* __restrict__ q1w, const float* __restrict__ q2w,
             const float* __restrict__ k1w, const float* __restrict__ k2w,
             const float* __restrict__ vw,  const float* __restrict__ outw,
             bf16_t* __restrict__ xb, bf16_t* __restrict__ encb,
             bf16_t* __restrict__ wq, bf16_t* __restrict__ wkv,
             bf16_t* __restrict__ wob)
{
    int idx = blockIdx.x * 256 + threadIdx.x;   // 0 .. 3670015
    const float* src; bf16_t* dst;
    if      (idx < 1048576) { src = x    + (size_t)idx * 4;              dst = xb   + (size_t)idx * 4; }
    else if (idx < 2097152) { src = enc  + (size_t)(idx - 1048576) * 4;  dst = encb + (size_t)(idx - 1048576) * 4; }
    else if (idx < 2359296) { src = q1w  + (size_t)(idx - 2097152) * 4;  dst = wq   + (size_t)(idx - 2097152) * 4; }
    else if (idx < 2621440) { src = q2w  + (size_t)(idx - 2359296) * 4;  dst = wq   + 1048576 + (size_t)(idx - 2359296) * 4; }
    else if (idx < 2883584) { src = k1w  + (size_t)(idx - 2621440) * 4;  dst = wkv  + (size_t)(idx - 2621440) * 4; }
    else if (idx < 3145728) { src = k2w  + (size_t)(idx - 2883584) * 4;  dst = wkv  + 1048576 + (size_t)(idx - 2883584) * 4; }
    else if (idx < 3407872) { src = vw   + (size_t)(idx - 3145728) * 4;  dst = wkv  + 2097152 + (size_t)(idx - 3145728) * 4; }
    else                    { src = outw + (size_t)(idx - 3407872) * 4;  dst = wob  + (size_t)(idx - 3407872) * 4; }
    float4 v = *(const float4*)src;
    bf16x4 o;
    o[0] = (bf16_t)v.x; o[1] = (bf16_t)v.y; o[2] = (bf16_t)v.z; o[3] = (bf16_t)v.w;
    *(bf16x4*)dst = o;
}

// ---------------------------------------------------------------------------
// Projection GEMM (m97 recipe, LINEAR dispatch -- the measured-65us config).
// C[m,n] = sum_k A[m,k] * W[n,k] + bias(n); scatter bf16 to [seg,b,h,t,d].
// grid x 0..15 -> q12 (N=2048), 16..39 -> k12v (N=3072); y = M-panel.
// ---------------------------------------------------------------------------
__global__ __launch_bounds__(256, 3)
void gemm_proj(const bf16_t* __restrict__ xb, const bf16_t* __restrict__ encb,
               const bf16_t* __restrict__ wq, const bf16_t* __restrict__ wkv,
               const float* __restrict__ q1b, const float* __restrict__ q2b,
               const float* __restrict__ k1b, const float* __restrict__ k2b,
               const float* __restrict__ vb,
               bf16_t* __restrict__ q12, bf16_t* __restrict__ k12v)
{
    __shared__ bf16_t sA[128 * 64];
    __shared__ bf16_t sB[128 * 64];
    int bx = blockIdx.x;
    const int blockM = blockIdx.y << 7;
    const bf16_t* A; const bf16_t* W; bf16_t* C; const float* bp; int blockN;
    if (bx < 16) {
        A = xb; W = wq; C = q12; blockN = bx << 7;
        bp = (blockN >> 10) ? q2b : q1b;
    } else {
        bx -= 16;
        A = encb; W = wkv; C = k12v; blockN = bx << 7;
        const int seg = blockN >> 10;
        bp = (seg == 0) ? k1b : ((seg == 1) ? k2b : vb);
    }

    const int tid = threadIdx.x;
    const int w = tid >> 6, lane = tid & 63;
    const int q = lane >> 4, r = lane & 15;
    const int wm = w & 1, wn = w >> 1;

    f32x4 acc[4][4];
#pragma unroll
    for (int i = 0; i < 4; ++i)
#pragma unroll
        for (int j = 0; j < 4; ++j) acc[i][j] = (f32x4){0.f, 0.f, 0.f, 0.f};

    for (int k0 = 0; k0 < 1024; k0 += 64) {
#pragma unroll
        for (int c = 0; c < 4; ++c) {
            const int s = c * 256 + tid;
            const int row = s >> 3;
            const int cg = (s & 7) ^ (row & 7);
            GLDS16(A + (size_t)(blockM + row) * 1024 + k0 + cg * 8, sA + c * 2048 + w * 512);
            GLDS16(W + (size_t)(blockN + row) * 1024 + k0 + cg * 8, sB + c * 2048 + w * 512);
        }
        __syncthreads();
#pragma unroll
        for (int ks = 0; ks < 2; ++ks) {
            bf16x8 a[4], b[4];
#pragma unroll
            for (int i = 0; i < 4; ++i) {
                const int row = wm * 64 + i * 16 + r;
                const int g = (ks * 4 + q) ^ (row & 7);
                a[i] = *(const bf16x8*)&sA[row * 64 + g * 8];
            }
#pragma unroll
            for (int j = 0; j < 4; ++j) {
                const int row = wn * 64 + j * 16 + r;
                const int g = (ks * 4 + q) ^ (row & 7);
                b[j] = *(const bf16x8*)&sB[row * 64 + g * 8];
            }
#pragma unroll
            for (int i = 0; i < 4; ++i)
#pragma unroll
                for (int j = 0; j < 4; ++j)
                    acc[i][j] = __builtin_amdgcn_mfma_f32_16x16x32_bf16(a[i], b[j], acc[i][j], 0, 0, 0);
        }
        __syncthreads();
    }

    const int seg = blockN >> 10;
#pragma unroll
    for (int j = 0; j < 4; ++j) {
        const int n = blockN + wn * 64 + j * 16 + r;
        const float bv = bp[n & 1023];
#pragma unroll
        for (int i = 0; i < 4; ++i) {
            f32x4 v = acc[i][j];
#pragma unroll
            for (int e = 0; e < 4; ++e) {
                const int m = blockM + wm * 64 + i * 16 + q * 4 + e;
                const float val = v[e] + bv;
                const int bb = m >> 10, t = m & 1023;
                const int h = (n >> 6) & 15, d = n & 63;
                ((bf16_t*)C)[((((size_t)seg * 4 + bb) * 16 + h) * 1024 + t) * 64 + d] = (bf16_t)val;
            }
        }
    }
}

// ---------------------------------------------------------------------------
// Output GEMM: BM=64 x BN=128 tile + bijective XCD swizzle (passed R2/R4).
// ---------------------------------------------------------------------------
__global__ __launch_bounds__(256, 4)
void gemm_out(const bf16_t* __restrict__ yb, const bf16_t* __restrict__ wob,
              const float* __restrict__ outb, float* __restrict__ out)
{
    __shared__ bf16_t sA[64 * 64];
    __shared__ bf16_t sB[128 * 64];
    const int L = blockIdx.x;
    const int xcd = L & 7, kk = L >> 3;
    const int blockM = (xcd * 8 + (kk >> 3)) * 64;
    const int blockN = (kk & 7) * 128;

    const int tid = threadIdx.x;
    const int w = tid >> 6, lane = tid & 63;
    const int q = lane >> 4, r = lane & 15;

    f32x4 acc[4][2];
#pragma unroll
    for (int i = 0; i < 4; ++i)
#pragma unroll
        for (int j = 0; j < 2; ++j) acc[i][j] = (f32x4){0.f, 0.f, 0.f, 0.f};

    for (int k0 = 0; k0 < 1024; k0 += 64) {
#pragma unroll
        for (int c = 0; c < 2; ++c) {
            const int s = c * 256 + tid;
            const int row = s >> 3;
            const int cg = (s & 7) ^ (row & 7);
            GLDS16(yb + (size_t)(blockM + row) * 1024 + k0 + cg * 8, sA + c * 2048 + w * 512);
        }
#pragma unroll
        for (int c = 0; c < 4; ++c) {
            const int s = c * 256 + tid;
            const int row = s >> 3;
            const int cg = (s & 7) ^ (row & 7);
            GLDS16(wob + (size_t)(blockN + row) * 1024 + k0 + cg * 8, sB + c * 2048 + w * 512);
        }
        __syncthreads();
#pragma unroll
        for (int ks = 0; ks < 2; ++ks) {
            bf16x8 a[4], b[2];
#pragma unroll
            for (int i = 0; i < 4; ++i) {
                const int row = i * 16 + r;
                const int g = (ks * 4 + q) ^ (row & 7);
                a[i] = *(const bf16x8*)&sA[row * 64 + g * 8];
            }
#pragma unroll
            for (int j = 0; j < 2; ++j) {
                const int row = w * 32 + j * 16 + r;
                const int g = (ks * 4 + q) ^ (row & 7);
                b[j] = *(const bf16x8*)&sB[row * 64 + g * 8];
            }
#pragma unroll
            for (int i = 0; i < 4; ++i)
#pragma unroll
                for (int j = 0; j < 2; ++j)
                    acc[i][j] = __builtin_amdgcn_mfma_f32_16x16x32_bf16(a[i], b[j], acc[i][j], 0, 0, 0);
        }
        __syncthreads();
    }

#pragma unroll
    for (int j = 0; j < 2; ++j) {
        const int n = blockN + w * 32 + j * 16 + r;
        const float bv = outb[n];
#pragma unroll
        for (int i = 0; i < 4; ++i) {
            f32x4 v = acc[i][j];
#pragma unroll
            for (int e = 0; e < 4; ++e) {
                const int m = blockM + i * 16 + q * 4 + e;
                out[(size_t)m * 1024 + n] = v[e] + bv;
            }
        }
    }
}

// ---------------------------------------------------------------------------
// Attention phase helpers (transposed-S, 32 q-rows per wave; wv = wave index
// within its stream, 0..3).
// ---------------------------------------------------------------------------
__device__ __forceinline__ void compute_S(const bf16_t* __restrict__ sK,
                                          const bf16x8 (&fQ)[2][2],
                                          f32x4 (&S)[4][2], int q, int r)
{
#pragma unroll
    for (int i = 0; i < 4; ++i)
#pragma unroll
        for (int j = 0; j < 2; ++j) S[i][j] = (f32x4){0.f, 0.f, 0.f, 0.f};
#pragma unroll
    for (int ks = 0; ks < 2; ++ks) {
        bf16x8 fK[4];
#pragma unroll
        for (int i = 0; i < 4; ++i) {
            const int row = i * 16 + r;
            const int g = (ks * 4 + q) ^ (row & 7);
            fK[i] = *(const bf16x8*)&sK[row * 64 + g * 8];
        }
        __builtin_amdgcn_s_setprio(1);
#pragma unroll
        for (int i = 0; i < 4; ++i)
#pragma unroll
            for (int j = 0; j < 2; ++j)
                S[i][j] = __builtin_amdgcn_mfma_f32_16x16x32_bf16(fK[i], fQ[j][ks], S[i][j], 0, 0, 0);
        __builtin_amdgcn_s_setprio(0);
    }
}

__device__ __forceinline__ void softmax_pw(f32x4 (&S)[4][2], bf16_t* __restrict__ sPt,
                                           float (&l)[2], int wv, int q, int r)
{
#pragma unroll
    for (int j = 0; j < 2; ++j) {
        const int t = wv * 32 + j * 16 + r;
        float part = 0.f;
#pragma unroll
        for (int i = 0; i < 4; ++i) {
            bf16x4 pk;
#pragma unroll
            for (int e = 0; e < 4; ++e) {
                const float p = __builtin_amdgcn_exp2f(S[i][j][e] * C_SCALE);
                part += p;
                pk[e] = (bf16_t)p;
            }
            const int sb = i * 16 + q * 4;
            const int g = (sb >> 3) ^ (t & 7);
            *(bf16x4*)&sPt[t * 64 + g * 8 + (sb & 7)] = pk;
        }
        l[j] += part;
    }
}

__device__ __forceinline__ void pv(const bf16_t* __restrict__ sPt,
                                   const bf16x8 (&fV)[4][2],
                                   f32x4 (&O)[2][4], int wv, int q, int r)
{
#pragma unroll
    for (int ks = 0; ks < 2; ++ks) {
        bf16x8 fP[2];
#pragma unroll
        for (int i2 = 0; i2 < 2; ++i2) {
            const int m = wv * 32 + i2 * 16 + r;
            const int g = (ks * 4 + q) ^ (m & 7);
            fP[i2] = *(const bf16x8*)&sPt[m * 64 + g * 8];
        }
        __builtin_amdgcn_s_setprio(1);
#pragma unroll
        for (int i2 = 0; i2 < 2; ++i2)
#pragma unroll
            for (int j = 0; j < 4; ++j)
                O[i2][j] = __builtin_amdgcn_mfma_f32_16x16x32_bf16(fP[i2], fV[j][ks], O[i2][j], 0, 0, 0);
        __builtin_amdgcn_s_setprio(0);
    }
}

// ---------------------------------------------------------------------------
// Fused dual-stream differential flash attention.
// 512 thr = 8 waves: waves 0-3 = stream 1 (Q1K1), waves 4-7 = stream 2 (Q2K2),
// each wave owns 32 q-rows of the SAME 128-row q-tile (no per-wave LDS-read
// amplification). LDS 73 KB -> 2 blocks/CU = 16 waves/CU (4/SIMD).
// Streams combined in-block via f32 exchange in the dead sPt area ->
// stats cross-term free, no combine kernel, no partial-O HBM traffic.
// Grid dim3(64, 8): x = bh (XCD-local K/V), y = qt.
// ---------------------------------------------------------------------------
__global__ __launch_bounds__(512, 4)
void diff_attn_fused8(const bf16_t* __restrict__ q12, const bf16_t* __restrict__ k12v,
                      const float* __restrict__ lam, bf16_t* __restrict__ out,
                      float* __restrict__ stats)
{
    __shared__ bf16_t sK1[2][64 * 64];
    __shared__ bf16_t sK2[2][64 * 64];
    __shared__ bf16_t sVt[64 * 64];      // [d][s], swizzled
    __shared__ bf16_t sPt[2][128 * 64];  // per-stream P strips; dead after loop
    __shared__ float  sl[2][128];
    __shared__ float  sred[16];

    const int tid = threadIdx.x;
    const int w = tid >> 6, lane = tid & 63;   // w in 0..7
    const int st_id = w >> 2;                  // stream 0/1
    const int wv = w & 3;                      // wave within stream
    const int q = lane >> 4, r = lane & 15;
    const int bh = blockIdx.x, qt = blockIdx.y;
    const float lamv = lam[bh & (Hn - 1)];

    const size_t HT = (size_t)TKn * DHn;       // 65536
    const bf16_t* qg = q12 + (size_t)(st_id * 64 + bh) * HT + (size_t)qt * 128 * DHn;
    const bf16_t* kg = k12v + (size_t)(st_id * 64 + bh) * HT;
    const bf16_t* k1g = k12v + (size_t)bh * HT;            // staged by all threads
    const bf16_t* k2g = k1g + 64 * HT;
    const bf16_t* vg  = k1g + 128 * HT;
    (void)kg;

    // Q fragments in registers (B-operand layout); stream via qg
    bf16x8 fQ[2][2];
#pragma unroll
    for (int j = 0; j < 2; ++j) {
        const int t = wv * 32 + j * 16 + r;
#pragma unroll
        for (int ks = 0; ks < 2; ++ks)
            fQ[j][ks] = *(const bf16x8*)(qg + (size_t)t * 64 + ks * 32 + q * 8);
    }

    f32x4 O[2][4];
    float l[2] = {0.f, 0.f};
#pragma unroll
    for (int i = 0; i < 2; ++i)
#pragma unroll
        for (int j = 0; j < 4; ++j) O[i][j] = (f32x4){0.f,0.f,0.f,0.f};

    const bf16_t* sKs = st_id ? &sK2[0][0] : &sK1[0][0];   // stream's K dbuf base
    bf16_t* sPs = &sPt[st_id][0];

    // ---- prologue: stage K1[0], K2[0] (buf 0) and V[0] ----
    {
        const int row = tid >> 3;
        const int cg = (tid & 7) ^ (row & 7);
        GLDS16(k1g + row * 64 + cg * 8, &sK1[0][tid * 8]);
        GLDS16(k2g + row * 64 + cg * 8, &sK2[0][tid * 8]);
        const int s = tid & 63;
        bf16x8 v0 = *(const bf16x8*)(vg + (size_t)s * 64 + w * 8);
        __syncthreads();   // GLDS drained (compiler vmcnt before barrier)
#pragma unroll
        for (int i = 0; i < 8; ++i) {
            const int d = w * 8 + i;
            sVt[d * 64 + (((s >> 3) ^ i) << 3) + (s & 7)] = v0[i];
        }
        __syncthreads();   // sVt visible
    }

    bf16x8 vr;
    for (int st = 0; st < TKn / 64; ++st) {
        const int cur = st & 1;
        // ---- prefetch next tile: K1/K2 via GLDS dbuf, V into registers ----
        if (st < 15) {
            const int row = tid >> 3;
            const int cg = (tid & 7) ^ (row & 7);
            GLDS16(k1g + (size_t)(st + 1) * 4096 + row * 64 + cg * 8, &sK1[cur ^ 1][tid * 8]);
            GLDS16(k2g + (size_t)(st + 1) * 4096 + row * 64 + cg * 8, &sK2[cur ^ 1][tid * 8]);
            vr = *(const bf16x8*)(vg + (size_t)(st + 1) * 4096 + (size_t)(tid & 63) * 64 + w * 8);
        }

        // ---- compute on current tile (per-stream, wave-private) ----
        {
            f32x4 S[4][2];
            compute_S(sKs + cur * 4096, fQ, S, q, r);
            softmax_pw(S, sPs, l, wv, q, r);
        }
        bf16x8 fV[4][2];
#pragma unroll
        for (int j = 0; j < 4; ++j)
#pragma unroll
            for (int ks = 0; ks < 2; ++ks) {
                const int d = j * 16 + r;
                const int g = (ks * 4 + q) ^ (d & 7);
                fV[j][ks] = *(const bf16x8*)&sVt[d * 64 + g * 8];
            }
        pv(sPs, fV, O, wv, q, r);

        __syncthreads();   // all waves done with sVt & sK[cur]; prefetches drained
        if (st < 15) {
            const int s = tid & 63;
#pragma unroll
            for (int i = 0; i < 8; ++i) {
                const int d = w * 8 + i;
                sVt[d * 64 + (((s >> 3) ^ i) << 3) + (s & 7)] = vr[i];
            }
            __syncthreads();   // sVt[st+1] visible
        }
    }

    // ---- l reduction across q-groups, per stream ----
#pragma unroll
    for (int j = 0; j < 2; ++j) {
        float v1 = l[j];
        v1 += __shfl_xor(v1, 16); v1 += __shfl_xor(v1, 32);
        if (q == 0) sl[st_id][wv * 32 + j * 16 + r] = v1;
    }
    __syncthreads();   // sl visible; sPt dead -> reuse as f32 exchange (32 KB)

    float* xchg = (float*)&sPt[0][0];   // [128][64] f32

    // ---- stream 2 publishes lam * O2 / l2 ----
    if (st_id == 1) {
#pragma unroll
        for (int i2 = 0; i2 < 2; ++i2)
#pragma unroll
            for (int e = 0; e < 4; ++e) {
                const int t = wv * 32 + i2 * 16 + q * 4 + e;
                const float inv2 = lamv / sl[1][t];
#pragma unroll
                for (int j = 0; j < 4; ++j)
                    xchg[t * 64 + j * 16 + r] = O[i2][j][e] * inv2;
            }
    }
    __syncthreads();

    // ---- stream 1 combines, stores, and emits GN partial sums ----
    float ssum = 0.f, ssq = 0.f;
    if (st_id == 0) {
        bf16_t* op = out + ((size_t)bh * TQn + (size_t)qt * 128) * DHn;
#pragma unroll
        for (int i2 = 0; i2 < 2; ++i2)
#pragma unroll
            for (int e = 0; e < 4; ++e) {
                const int t = wv * 32 + i2 * 16 + q * 4 + e;
                const float inv1 = 1.0f / sl[0][t];
#pragma unroll
                for (int j = 0; j < 4; ++j) {
                    const float o = O[i2][j][e] * inv1 - xchg[t * 64 + j * 16 + r];
                    op[(size_t)t * 64 + j * 16 + r] = (bf16_t)o;
                    ssum += o;
                    ssq += o * o;
                }
            }
#pragma unroll
        for (int d = 1; d < 64; d <<= 1) {
            ssum += __shfl_xor(ssum, d);
            ssq  += __shfl_xor(ssq, d);
        }
        if (lane == 0) { sred[wv] = ssum; sred[8 + wv] = ssq; }
    }
    __syncthreads();
    if (tid == 0) {
        stats[(bh << 3) + qt]       = sred[0] + sred[1] + sred[2] + sred[3];
        stats[512 + (bh << 3) + qt] = sred[8] + sred[9] + sred[10] + sred[11];
    }
}

// ---------------------------------------------------------------------------
// GroupNorm apply (mu/rstd from per-(bh,qt) partials) + transpose -> y bf16
// ---------------------------------------------------------------------------
__global__ __launch_bounds__(256)
void gn_apply(const bf16_t* __restrict__ attn, const float* __restrict__ stats,
              const float* __restrict__ gamma, const float* __restrict__ beta,
              bf16_t* __restrict__ y)
{
    const int f = blockIdx.x * 256 + threadIdx.x;   // 8-elem group, 0..524287
    const int d8 = (f & 7) << 3;
    const int t  = (f >> 3) & 1023;
    const int bh = f >> 13;
    const int h  = bh & 15;
    const int b  = bh >> 4;
    const float* p1 = stats + (bh << 3);
    const float* p2 = stats + 512 + (bh << 3);
    float s1 = 0.f, s2 = 0.f;
#pragma unroll
    for (int k = 0; k < 8; ++k) { s1 += p1[k]; s2 += p2[k]; }
    const float mu = s1 * (1.f / 65536.f);
    const float var = s2 * (1.f / 65536.f) - mu * mu;
    const float rstd = rsqrtf(var + EPSv);
    bf16x8 v = *(const bf16x8*)&attn[((size_t)bh << 16) + t * 64 + d8];
    const int c = h * 64 + d8;
    const float* gp = gamma + c;
    const float* bp = beta + c;
    bf16x8 o;
#pragma unroll
    for (int i = 0; i < 8; ++i)
        o[i] = (bf16_t)(((float)v[i] - mu) * rstd * gp[i] + bp[i]);
    *(bf16x8*)&y[((size_t)(b * 1024 + t)) * 1024 + c] = o;
}

// ---------------------------------------------------------------------------
extern "C" void kernel_launch(void* const* d_in, const int* in_sizes, int n_in,
                              void* d_out, int out_size, void* d_ws, size_t ws_size,
                              hipStream_t stream)
{
    const float* x    = (const float*)d_in[0];
    const float* enc  = (const float*)d_in[1];
    const float* Q1w  = (const float*)d_in[2];
    const float* Q1b  = (const float*)d_in[3];
    const float* Q2w  = (const float*)d_in[4];
    const float* Q2b  = (const float*)d_in[5];
    const float* K1w  = (const float*)d_in[6];
    const float* K1b  = (const float*)d_in[7];
    const float* K2w  = (const float*)d_in[8];
    const float* K2b  = (const float*)d_in[9];
    const float* Vw   = (const float*)d_in[10];
    const float* Vb   = (const float*)d_in[11];
    const float* lam  = (const float*)d_in[12];
    const float* gng  = (const float*)d_in[13];
    const float* gnb  = (const float*)d_in[14];
    const float* outw = (const float*)d_in[15];
    const float* outb = (const float*)d_in[16];
    float* out = (float*)d_out;

    // workspace layout (bf16 elems). Peak footprint 68 MB.
    bf16_t* xb   = (bf16_t*)d_ws;            // 4,194,304   live k1..k2
    bf16_t* encb = xb   + 4194304;           // 4,194,304   live k1..k2
    bf16_t* wq   = encb + 4194304;           // 2,097,152   live k1..k2  [Q1w|Q2w]
    bf16_t* wkv  = wq   + 2097152;           // 3,145,728   live k1..k2  [K1w|K2w|Vw]
    bf16_t* wob  = wkv  + 3145728;           // 1,048,576   live k1..k5
    bf16_t* q12  = wob  + 1048576;           // 8,388,608   live k2..k3  [2][B][H][T][D]
    bf16_t* k12v = q12  + 8388608;           // 12,582,912  live k2..k3  [3][B][H][T][D]
    bf16_t* attnb= xb;                       // alias: written k3, read k4 (xb dead)
    bf16_t* yb   = encb;                     // alias: written k4, read k5 (encb dead)
    float*  stats= (float*)wq;               // alias: 1024 fp32, written k3, read k4 (wq dead)

    cvt_all<<<14336, 256, 0, stream>>>(x, enc, Q1w, Q2w, K1w, K2w, Vw, outw,
                                       xb, encb, wq, wkv, wob);

    gemm_proj<<<dim3(40, 32), 256, 0, stream>>>(xb, encb, wq, wkv,
                                                Q1b, Q2b, K1b, K2b, Vb, q12, k12v);

    diff_attn_fused8<<<dim3(64, 8), 512, 0, stream>>>(q12, k12v, lam, attnb, stats);

    gn_apply<<<2048, 256, 0, stream>>>(attnb, stats, gng, gnb, yb);

    gemm_out<<<512, 256, 0, stream>>>(yb, wob, outb, out);
}

// Round 6
// 249.399 us; speedup vs baseline: 1.0642x; 1.0006x over previous
//
#include <hip/hip_runtime.h>
#include <cmath>

typedef __bf16 bf16_t;
typedef bf16_t bf16x8 __attribute__((ext_vector_type(8)));
typedef bf16_t bf16x4 __attribute__((ext_vector_type(4)));
typedef float  f32x4  __attribute__((ext_vector_type(4)));
typedef float  f32x16 __attribute__((ext_vector_type(16)));
typedef unsigned int u32x4v __attribute__((ext_vector_type(4)));

#define Bn  4
#define TQn 1024
#define TKn 1024
#define En  1024
#define Hn  16
#define DHn 64

static constexpr float EPSv = 1e-5f;
// softmax in exp2 domain: scale = (1/sqrt(64)) * log2(e)
static constexpr float C_SCALE = 0.18033688011112042f;

#define GLDS16(g, l)                                                         \
    __builtin_amdgcn_global_load_lds(                                        \
        (const __attribute__((address_space(1))) void*)(g),                  \
        (__attribute__((address_space(3))) void*)(l), 16, 0, 0)

// ---------------------------------------------------------------------------
// fp32 -> bf16 conversion, all tensors fused.
// ---------------------------------------------------------------------------
__global__ __launch_bounds__(256)
void cvt_all(const float* __restrict__ x, const float* __restrict__ enc,
             const float* __restrict__ q1w, const float* __restrict__ q2w,
             const float* __restrict__ k1w, const float* __restrict__ k2w,
             const float* __restrict__ vw,  const float* __restrict__ outw,
             bf16_t* __restrict__ xb, bf16_t* __restrict__ encb,
             bf16_t* __restrict__ wq, bf16_t* __restrict__ wkv,
             bf16_t* __restrict__ wob)
{
    int idx = blockIdx.x * 256 + threadIdx.x;   // 0 .. 3670015
    const float* src; bf16_t* dst;
    if      (idx < 1048576) { src = x    + (size_t)idx * 4;              dst = xb   + (size_t)idx * 4; }
    else if (idx < 2097152) { src = enc  + (size_t)(idx - 1048576) * 4;  dst = encb + (size_t)(idx - 1048576) * 4; }
    else if (idx < 2359296) { src = q1w  + (size_t)(idx - 2097152) * 4;  dst = wq   + (size_t)(idx - 2097152) * 4; }
    else if (idx < 2621440) { src = q2w  + (size_t)(idx - 2359296) * 4;  dst = wq   + 1048576 + (size_t)(idx - 2359296) * 4; }
    else if (idx < 2883584) { src = k1w  + (size_t)(idx - 2621440) * 4;  dst = wkv  + (size_t)(idx - 2621440) * 4; }
    else if (idx < 3145728) { src = k2w  + (size_t)(idx - 2883584) * 4;  dst = wkv  + 1048576 + (size_t)(idx - 2883584) * 4; }
    else if (idx < 3407872) { src = vw   + (size_t)(idx - 3145728) * 4;  dst = wkv  + 2097152 + (size_t)(idx - 3145728) * 4; }
    else                    { src = outw + (size_t)(idx - 3407872) * 4;  dst = wob  + (size_t)(idx - 3407872) * 4; }
    float4 v = *(const float4*)src;
    bf16x4 o;
    o[0] = (bf16_t)v.x; o[1] = (bf16_t)v.y; o[2] = (bf16_t)v.z; o[3] = (bf16_t)v.w;
    *(bf16x4*)dst = o;
}

// ---------------------------------------------------------------------------
// Projection GEMM (m97 recipe, linear dispatch) + NEW coalesced epilogue:
// C-tile staged into LDS (XOR-swizzled, overlays dead sA/sB) then written as
// full 128B lines (WRITE_SIZE was 2.9x amplified by the b,h,t,d b16 scatter).
// ---------------------------------------------------------------------------
__global__ __launch_bounds__(256, 3)
void gemm_proj(const bf16_t* __restrict__ xb, const bf16_t* __restrict__ encb,
               const bf16_t* __restrict__ wq, const bf16_t* __restrict__ wkv,
               const float* __restrict__ q1b, const float* __restrict__ q2b,
               const float* __restrict__ k1b, const float* __restrict__ k2b,
               const float* __restrict__ vb,
               bf16_t* __restrict__ q12, bf16_t* __restrict__ k12v)
{
    __shared__ __align__(16) bf16_t sAB[2][128 * 64];
    bf16_t* const sA = &sAB[0][0];
    bf16_t* const sB = &sAB[1][0];
    bf16_t* const sC = &sAB[0][0];      // epilogue overlay [128][128]

    int bx = blockIdx.x;
    const int blockM = blockIdx.y << 7;
    const bf16_t* A; const bf16_t* W; bf16_t* C; const float* bp; int blockN;
    if (bx < 16) {
        A = xb; W = wq; C = q12; blockN = bx << 7;
        bp = (blockN >> 10) ? q2b : q1b;
    } else {
        bx -= 16;
        A = encb; W = wkv; C = k12v; blockN = bx << 7;
        const int seg0 = blockN >> 10;
        bp = (seg0 == 0) ? k1b : ((seg0 == 1) ? k2b : vb);
    }

    const int tid = threadIdx.x;
    const int w = tid >> 6, lane = tid & 63;
    const int q = lane >> 4, r = lane & 15;
    const int wm = w & 1, wn = w >> 1;

    f32x4 acc[4][4];
#pragma unroll
    for (int i = 0; i < 4; ++i)
#pragma unroll
        for (int j = 0; j < 4; ++j) acc[i][j] = (f32x4){0.f, 0.f, 0.f, 0.f};

    for (int k0 = 0; k0 < 1024; k0 += 64) {
#pragma unroll
        for (int c = 0; c < 4; ++c) {
            const int s = c * 256 + tid;
            const int row = s >> 3;
            const int cg = (s & 7) ^ (row & 7);
            GLDS16(A + (size_t)(blockM + row) * 1024 + k0 + cg * 8, sA + c * 2048 + w * 512);
            GLDS16(W + (size_t)(blockN + row) * 1024 + k0 + cg * 8, sB + c * 2048 + w * 512);
        }
        __syncthreads();
#pragma unroll
        for (int ks = 0; ks < 2; ++ks) {
            bf16x8 a[4], b[4];
#pragma unroll
            for (int i = 0; i < 4; ++i) {
                const int row = wm * 64 + i * 16 + r;
                const int g = (ks * 4 + q) ^ (row & 7);
                a[i] = *(const bf16x8*)&sA[row * 64 + g * 8];
            }
#pragma unroll
            for (int j = 0; j < 4; ++j) {
                const int row = wn * 64 + j * 16 + r;
                const int g = (ks * 4 + q) ^ (row & 7);
                b[j] = *(const bf16x8*)&sB[row * 64 + g * 8];
            }
#pragma unroll
            for (int i = 0; i < 4; ++i)
#pragma unroll
                for (int j = 0; j < 4; ++j)
                    acc[i][j] = __builtin_amdgcn_mfma_f32_16x16x32_bf16(a[i], b[j], acc[i][j], 0, 0, 0);
        }
        __syncthreads();
    }

    // ---- epilogue: stage to LDS (swizzled), then coalesced 16B stores ----
#pragma unroll
    for (int j = 0; j < 4; ++j) {
        const int n = wn * 64 + j * 16 + r;             // 0..127 local
        const float bv = bp[(blockN + n) & 1023];
#pragma unroll
        for (int i = 0; i < 4; ++i) {
            f32x4 v = acc[i][j];
#pragma unroll
            for (int e = 0; e < 4; ++e) {
                const int m = wm * 64 + i * 16 + q * 4 + e;
                sC[m * 128 + (((n >> 3) ^ (m & 7)) << 3) + (n & 7)] = (bf16_t)(v[e] + bv);
            }
        }
    }
    __syncthreads();
    const int seg = blockN >> 10;
#pragma unroll
    for (int v8 = 0; v8 < 8; ++v8) {
        const int flat = v8 * 256 + tid;    // 0..2047
        const int m = flat >> 4;            // tile row
        const int nb = flat & 15;           // 16B col-block
        bf16x8 row = *(const bf16x8*)&sC[m * 128 + ((nb ^ (m & 7)) << 3)];
        const int gm = blockM + m, gn = blockN + nb * 8;
        const int bb = gm >> 10, t = gm & 1023;
        const int h = (gn >> 6) & 15, d = gn & 63;
        *(bf16x8*)&C[((((size_t)seg * 4 + bb) * 16 + h) * 1024 + t) * 64 + d] = row;
    }
}

// ---------------------------------------------------------------------------
// Output GEMM: BM=64 x BN=128 tile + bijective XCD swizzle (unchanged).
// ---------------------------------------------------------------------------
__global__ __launch_bounds__(256, 4)
void gemm_out(const bf16_t* __restrict__ yb, const bf16_t* __restrict__ wob,
              const float* __restrict__ outb, float* __restrict__ out)
{
    __shared__ bf16_t sA[64 * 64];
    __shared__ bf16_t sB[128 * 64];
    const int L = blockIdx.x;
    const int xcd = L & 7, kk = L >> 3;
    const int blockM = (xcd * 8 + (kk >> 3)) * 64;
    const int blockN = (kk & 7) * 128;

    const int tid = threadIdx.x;
    const int w = tid >> 6, lane = tid & 63;
    const int q = lane >> 4, r = lane & 15;

    f32x4 acc[4][2];
#pragma unroll
    for (int i = 0; i < 4; ++i)
#pragma unroll
        for (int j = 0; j < 2; ++j) acc[i][j] = (f32x4){0.f, 0.f, 0.f, 0.f};

    for (int k0 = 0; k0 < 1024; k0 += 64) {
#pragma unroll
        for (int c = 0; c < 2; ++c) {
            const int s = c * 256 + tid;
            const int row = s >> 3;
            const int cg = (s & 7) ^ (row & 7);
            GLDS16(yb + (size_t)(blockM + row) * 1024 + k0 + cg * 8, sA + c * 2048 + w * 512);
        }
#pragma unroll
        for (int c = 0; c < 4; ++c) {
            const int s = c * 256 + tid;
            const int row = s >> 3;
            const int cg = (s & 7) ^ (row & 7);
            GLDS16(wob + (size_t)(blockN + row) * 1024 + k0 + cg * 8, sB + c * 2048 + w * 512);
        }
        __syncthreads();
#pragma unroll
        for (int ks = 0; ks < 2; ++ks) {
            bf16x8 a[4], b[2];
#pragma unroll
            for (int i = 0; i < 4; ++i) {
                const int row = i * 16 + r;
                const int g = (ks * 4 + q) ^ (row & 7);
                a[i] = *(const bf16x8*)&sA[row * 64 + g * 8];
            }
#pragma unroll
            for (int j = 0; j < 2; ++j) {
                const int row = w * 32 + j * 16 + r;
                const int g = (ks * 4 + q) ^ (row & 7);
                b[j] = *(const bf16x8*)&sB[row * 64 + g * 8];
            }
#pragma unroll
            for (int i = 0; i < 4; ++i)
#pragma unroll
                for (int j = 0; j < 2; ++j)
                    acc[i][j] = __builtin_amdgcn_mfma_f32_16x16x32_bf16(a[i], b[j], acc[i][j], 0, 0, 0);
        }
        __syncthreads();
    }

#pragma unroll
    for (int j = 0; j < 2; ++j) {
        const int n = blockN + w * 32 + j * 16 + r;
        const float bv = outb[n];
#pragma unroll
        for (int i = 0; i < 4; ++i) {
            f32x4 v = acc[i][j];
#pragma unroll
            for (int e = 0; e < 4; ++e) {
                const int m = blockM + i * 16 + q * 4 + e;
                out[(size_t)m * 1024 + n] = v[e] + bv;
            }
        }
    }
}

// ---------------------------------------------------------------------------
// In-register P helpers (T12): cvt_pk + permlane32_swap.
// ---------------------------------------------------------------------------
__device__ __forceinline__ unsigned cvtpk_bf16(float a, float b)
{
    unsigned r;
    asm("v_cvt_pk_bf16_f32 %0, %1, %2" : "=v"(r) : "v"(a), "v"(b));
    return r;
}

// Build the two K=16 A-fragments (PA covering kv 0..15 and 16..31 of a 32-kv
// block) from the 16 per-lane P values (layout: p[reg] = P[q=lane&31]
// [kv = (reg&3) + 8*(reg>>2) + 4*(lane>>5)]).
__device__ __forceinline__ void pack_pa(const f32x16& p, bf16x8& pa0, bf16x8& pa1)
{
    unsigned a0 = cvtpk_bf16(p[0], p[1]),   b0 = cvtpk_bf16(p[4], p[5]);
    asm("v_permlane32_swap_b32 %0, %1" : "+v"(a0), "+v"(b0));
    unsigned a1 = cvtpk_bf16(p[2], p[3]),   b1 = cvtpk_bf16(p[6], p[7]);
    asm("v_permlane32_swap_b32 %0, %1" : "+v"(a1), "+v"(b1));
    pa0 = __builtin_bit_cast(bf16x8, (u32x4v){a0, a1, b0, b1});
    unsigned a2 = cvtpk_bf16(p[8], p[9]),   b2 = cvtpk_bf16(p[12], p[13]);
    asm("v_permlane32_swap_b32 %0, %1" : "+v"(a2), "+v"(b2));
    unsigned a3 = cvtpk_bf16(p[10], p[11]), b3 = cvtpk_bf16(p[14], p[15]);
    asm("v_permlane32_swap_b32 %0, %1" : "+v"(a3), "+v"(b3));
    pa1 = __builtin_bit_cast(bf16x8, (u32x4v){a2, a3, b2, b3});
}

// ---------------------------------------------------------------------------
// Dual-stream differential flash attention, 32x32 MFMA, in-register P.
// 512 thr = 8 waves: waves 0-3 stream 1, waves 4-7 stream 2; each wave owns
// 32 q-rows. Swapped QK^T (mfma(K,Q)) -> P lane-local -> cvt_pk+permlane into
// PV A-fragments: NO P round-trip through LDS (the measured serial-path wall).
// LDS 41 KB arena (sK1 dbuf | sK2 dbuf | sVt); epilogue f32 exchange overlays
// the dead sK region. Grid dim3(64, 8): x = bh (XCD-local K/V), y = qt.
// ---------------------------------------------------------------------------
__global__ __launch_bounds__(512, 4)
void diff_attn32(const bf16_t* __restrict__ q12, const bf16_t* __restrict__ k12v,
                 const float* __restrict__ lam, bf16_t* __restrict__ out,
                 float* __restrict__ stats)
{
    __shared__ __align__(16) bf16_t arena[20480];   // 40 KB
    bf16_t* const sK1 = arena;                      // [2][64*64] dbuf
    bf16_t* const sK2 = arena + 8192;               // [2][64*64] dbuf
    bf16_t* const sVt = arena + 16384;              // [64][64] transposed V
    float*  const xchg = (float*)arena;             // epilogue overlay [128][64]
    __shared__ float sl[2][128];
    __shared__ float sred[16];

    const int tid = threadIdx.x;
    const int w = tid >> 6, lane = tid & 63;        // w 0..7
    const int st_id = w >> 2, wv = w & 3;           // stream, wave-in-stream
    const int hi = lane >> 5, lo = lane & 31;
    const int bh = blockIdx.x, qt = blockIdx.y;
    const float lamv = lam[bh & (Hn - 1)];

    const size_t HT = (size_t)TKn * DHn;            // 65536
    const bf16_t* qg  = q12 + (size_t)(st_id * 64 + bh) * HT + (size_t)qt * 128 * DHn;
    const bf16_t* k1g = k12v + (size_t)bh * HT;
    const bf16_t* k2g = k1g + 64 * HT;
    const bf16_t* vg  = k1g + 128 * HT;
    const bf16_t* const sKs = st_id ? sK2 : sK1;

    // Q fragments (B-operand, 32x32x16): lane needs Q[q=wv*32+lo][dk*16+hi*8+..]
    bf16x8 fQ[4];
#pragma unroll
    for (int dk = 0; dk < 4; ++dk)
        fQ[dk] = *(const bf16x8*)(qg + (size_t)(wv * 32 + lo) * 64 + dk * 16 + hi * 8);

    f32x16 O0, O1;
#pragma unroll
    for (int e = 0; e < 16; ++e) { O0[e] = 0.f; O1[e] = 0.f; }
    float lsum = 0.f;

    // ---- prologue: stage K1[0], K2[0] and V[0] ----
    {
        const int row = tid >> 3;
        const int cg = (tid & 7) ^ (row & 7);
        GLDS16(k1g + row * 64 + cg * 8, sK1 + tid * 8);
        GLDS16(k2g + row * 64 + cg * 8, sK2 + tid * 8);
        const int s = tid & 63;
        bf16x8 v0 = *(const bf16x8*)(vg + (size_t)s * 64 + w * 8);
        __syncthreads();    // GLDS drained
#pragma unroll
        for (int i = 0; i < 8; ++i) {
            const int d = w * 8 + i;
            sVt[d * 64 + (((s >> 3) ^ i) << 3) + (s & 7)] = v0[i];
        }
        __syncthreads();    // sVt visible
    }

    bf16x8 vr;
    for (int st = 0; st < TKn / 64; ++st) {
        const int cur = st & 1;
        // ---- prefetch next tile ----
        if (st < 15) {
            const int row = tid >> 3;
            const int cg = (tid & 7) ^ (row & 7);
            GLDS16(k1g + (size_t)(st + 1) * 4096 + row * 64 + cg * 8, sK1 + (cur ^ 1) * 4096 + tid * 8);
            GLDS16(k2g + (size_t)(st + 1) * 4096 + row * 64 + cg * 8, sK2 + (cur ^ 1) * 4096 + tid * 8);
            vr = *(const bf16x8*)(vg + (size_t)(st + 1) * 4096 + (size_t)(tid & 63) * 64 + w * 8);
        }

        const bf16_t* sKc = sKs + cur * 4096;
#pragma unroll
        for (int kb = 0; kb < 2; ++kb) {
            // ---- S = K * Q^T (swapped): C[kv][q], 4 chained mfma over d ----
            f32x16 S;
#pragma unroll
            for (int e = 0; e < 16; ++e) S[e] = 0.f;
            __builtin_amdgcn_s_setprio(1);
#pragma unroll
            for (int dk = 0; dk < 4; ++dk) {
                bf16x8 fk = *(const bf16x8*)&sKc[(kb * 32 + lo) * 64 + (((dk * 2 + hi) ^ (lo & 7)) << 3)];
                S = __builtin_amdgcn_mfma_f32_32x32x16_bf16(fk, fQ[dk], S, 0, 0, 0);
            }
            __builtin_amdgcn_s_setprio(0);
            // ---- softmax numerator in-place + row-partial l ----
#pragma unroll
            for (int e = 0; e < 16; ++e) {
                S[e] = __builtin_amdgcn_exp2f(S[e] * C_SCALE);
                lsum += S[e];
            }
            // ---- P -> bf16 A-fragments, in registers ----
            bf16x8 pa0, pa1;
            pack_pa(S, pa0, pa1);
            // ---- PV: O[q][d] += P * V ----
            const int c0 = ((kb * 4 + 0 * 2 + hi) ^ (lo & 7)) << 3;   // ks=2kb
            const int c1 = ((kb * 4 + 1 * 2 + hi) ^ (lo & 7)) << 3;   // ks=2kb+1
            bf16x8 fv00 = *(const bf16x8*)&sVt[(0 * 32 + lo) * 64 + c0];
            bf16x8 fv01 = *(const bf16x8*)&sVt[(0 * 32 + lo) * 64 + c1];
            bf16x8 fv10 = *(const bf16x8*)&sVt[(1 * 32 + lo) * 64 + c0];
            bf16x8 fv11 = *(const bf16x8*)&sVt[(1 * 32 + lo) * 64 + c1];
            __builtin_amdgcn_s_setprio(1);
            O0 = __builtin_amdgcn_mfma_f32_32x32x16_bf16(pa0, fv00, O0, 0, 0, 0);
            O0 = __builtin_amdgcn_mfma_f32_32x32x16_bf16(pa1, fv01, O0, 0, 0, 0);
            O1 = __builtin_amdgcn_mfma_f32_32x32x16_bf16(pa0, fv10, O1, 0, 0, 0);
            O1 = __builtin_amdgcn_mfma_f32_32x32x16_bf16(pa1, fv11, O1, 0, 0, 0);
            __builtin_amdgcn_s_setprio(0);
        }

        __syncthreads();    // sK/sVt consumers done; prefetches drained
        if (st < 15) {
            const int s = tid & 63;
#pragma unroll
            for (int i = 0; i < 8; ++i) {
                const int d = w * 8 + i;
                sVt[d * 64 + (((s >> 3) ^ i) << 3) + (s & 7)] = vr[i];
            }
            __syncthreads();    // sVt[st+1] visible
        }
    }

    // ---- row-sum l: halves live in lane and lane^32 ----
    lsum += __shfl_xor(lsum, 32);
    if (hi == 0) sl[st_id][wv * 32 + lo] = lsum;   // same-wave read below, no barrier needed

    // ---- stream 2 publishes lam * O2 / l2 into the dead sK arena ----
    if (st_id == 1) {
#pragma unroll
        for (int reg = 0; reg < 16; ++reg) {
            const int t = wv * 32 + (reg & 3) + 8 * (reg >> 2) + 4 * hi;
            const float inv2 = lamv / sl[1][t];
            xchg[t * 64 + lo]      = O0[reg] * inv2;
            xchg[t * 64 + 32 + lo] = O1[reg] * inv2;
        }
    }
    __syncthreads();

    // ---- stream 1 combines, stores (64B-coalesced), emits GN partials ----
    if (st_id == 0) {
        float ssum = 0.f, ssq = 0.f;
        bf16_t* op = out + ((size_t)bh * TQn + (size_t)qt * 128) * DHn;
#pragma unroll
        for (int reg = 0; reg < 16; ++reg) {
            const int t = wv * 32 + (reg & 3) + 8 * (reg >> 2) + 4 * hi;
            const float inv1 = 1.0f / sl[0][t];
            const float o0 = O0[reg] * inv1 - xchg[t * 64 + lo];
            const float o1 = O1[reg] * inv1 - xchg[t * 64 + 32 + lo];
            op[(size_t)t * 64 + lo]      = (bf16_t)o0;
            op[(size_t)t * 64 + 32 + lo] = (bf16_t)o1;
            ssum += o0 + o1;
            ssq  += o0 * o0 + o1 * o1;
        }
#pragma unroll
        for (int d = 1; d < 64; d <<= 1) {
            ssum += __shfl_xor(ssum, d);
            ssq  += __shfl_xor(ssq, d);
        }
        if (lane == 0) { sred[wv] = ssum; sred[8 + wv] = ssq; }
    }
    __syncthreads();
    if (tid == 0) {
        stats[(bh << 3) + qt]       = sred[0] + sred[1] + sred[2] + sred[3];
        stats[512 + (bh << 3) + qt] = sred[8] + sred[9] + sred[10] + sred[11];
    }
}

// ---------------------------------------------------------------------------
// GroupNorm apply (mu/rstd from per-(bh,qt) partials) + transpose -> y bf16
// ---------------------------------------------------------------------------
__global__ __launch_bounds__(256)
void gn_apply(const bf16_t* __restrict__ attn, const float* __restrict__ stats,
              const float* __restrict__ gamma, const float* __restrict__ beta,
              bf16_t* __restrict__ y)
{
    const int f = blockIdx.x * 256 + threadIdx.x;   // 8-elem group, 0..524287
    const int d8 = (f & 7) << 3;
    const int t  = (f >> 3) & 1023;
    const int bh = f >> 13;
    const int h  = bh & 15;
    const int b  = bh >> 4;
    const float* p1 = stats + (bh << 3);
    const float* p2 = stats + 512 + (bh << 3);
    float s1 = 0.f, s2 = 0.f;
#pragma unroll
    for (int k = 0; k < 8; ++k) { s1 += p1[k]; s2 += p2[k]; }
    const float mu = s1 * (1.f / 65536.f);
    const float var = s2 * (1.f / 65536.f) - mu * mu;
    const float rstd = rsqrtf(var + EPSv);
    bf16x8 v = *(const bf16x8*)&attn[((size_t)bh << 16) + t * 64 + d8];
    const int c = h * 64 + d8;
    const float* gp = gamma + c;
    const float* bp = beta + c;
    bf16x8 o;
#pragma unroll
    for (int i = 0; i < 8; ++i)
        o[i] = (bf16_t)(((float)v[i] - mu) * rstd * gp[i] + bp[i]);
    *(bf16x8*)&y[((size_t)(b * 1024 + t)) * 1024 + c] = o;
}

// ---------------------------------------------------------------------------
extern "C" void kernel_launch(void* const* d_in, const int* in_sizes, int n_in,
                              void* d_out, int out_size, void* d_ws, size_t ws_size,
                              hipStream_t stream)
{
    const float* x    = (const float*)d_in[0];
    const float* enc  = (const float*)d_in[1];
    const float* Q1w  = (const float*)d_in[2];
    const float* Q1b  = (const float*)d_in[3];
    const float* Q2w  = (const float*)d_in[4];
    const float* Q2b  = (const float*)d_in[5];
    const float* K1w  = (const float*)d_in[6];
    const float* K1b  = (const float*)d_in[7];
    const float* K2w  = (const float*)d_in[8];
    const float* K2b  = (const float*)d_in[9];
    const float* Vw   = (const float*)d_in[10];
    const float* Vb   = (const float*)d_in[11];
    const float* lam  = (const float*)d_in[12];
    const float* gng  = (const float*)d_in[13];
    const float* gnb  = (const float*)d_in[14];
    const float* outw = (const float*)d_in[15];
    const float* outb = (const float*)d_in[16];
    float* out = (float*)d_out;

    // workspace layout (bf16 elems). Peak footprint 68 MB.
    bf16_t* xb   = (bf16_t*)d_ws;            // 4,194,304   live k1..k2
    bf16_t* encb = xb   + 4194304;           // 4,194,304   live k1..k2
    bf16_t* wq   = encb + 4194304;           // 2,097,152   live k1..k2  [Q1w|Q2w]
    bf16_t* wkv  = wq   + 2097152;           // 3,145,728   live k1..k2  [K1w|K2w|Vw]
    bf16_t* wob  = wkv  + 3145728;           // 1,048,576   live k1..k5
    bf16_t* q12  = wob  + 1048576;           // 8,388,608   live k2..k3  [2][B][H][T][D]
    bf16_t* k12v = q12  + 8388608;           // 12,582,912  live k2..k3  [3][B][H][T][D]
    bf16_t* attnb= xb;                       // alias: written k3, read k4 (xb dead)
    bf16_t* yb   = encb;                     // alias: written k4, read k5 (encb dead)
    float*  stats= (float*)wq;               // alias: 1024 fp32, written k3, read k4 (wq dead)

    cvt_all<<<14336, 256, 0, stream>>>(x, enc, Q1w, Q2w, K1w, K2w, Vw, outw,
                                       xb, encb, wq, wkv, wob);

    gemm_proj<<<dim3(40, 32), 256, 0, stream>>>(xb, encb, wq, wkv,
                                                Q1b, Q2b, K1b, K2b, Vb, q12, k12v);

    diff_attn32<<<dim3(64, 8), 512, 0, stream>>>(q12, k12v, lam, attnb, stats);

    gn_apply<<<2048, 256, 0, stream>>>(attnb, stats, gng, gnb, yb);

    gemm_out<<<512, 256, 0, stream>>>(yb, wob, outb, out);
}